// Round 8
// baseline (1172.320 us; speedup 1.0000x reference)
//
#include <hip/hip_runtime.h>
#include <math.h>

#define N_NODES 100000
#define N_EDGES 3200000
#define H 32
#define SCAN_BLOCKS ((N_NODES + 255) / 256)   // 391
#define LDS_STRIDE 33                         // conflict-free: bank = (row+lane)%32

__device__ __forceinline__ float lrelu(float v) { return v > 0.0f ? v : 0.01f * v; }

// out = bias + in @ W   (W is [H,H] row-major: W[k*H+o]); uniform W/bias -> s_loads
__device__ __forceinline__ void matvec32(const float* __restrict__ in,
                                         const float* __restrict__ W,
                                         const float* __restrict__ bias,
                                         float* __restrict__ out) {
#pragma unroll
    for (int o = 0; o < H; ++o) out[o] = bias[o];
#pragma unroll
    for (int k = 0; k < H; ++k) {
        float v = in[k];
#pragma unroll
        for (int o = 0; o < H; ++o) out[o] = fmaf(v, W[k * H + o], out[o]);
    }
}

// out += in @ W
__device__ __forceinline__ void matvec32_acc(const float* __restrict__ in,
                                             const float* __restrict__ W,
                                             float* __restrict__ out) {
#pragma unroll
    for (int k = 0; k < H; ++k) {
        float v = in[k];
#pragma unroll
        for (int o = 0; o < H; ++o) out[o] = fmaf(v, W[k * H + o], out[o]);
    }
}

__device__ __forceinline__ void load_row32(const float* __restrict__ p, float* __restrict__ r) {
    const float4* p4 = reinterpret_cast<const float4*>(p);
#pragma unroll
    for (int q = 0; q < 8; ++q) {
        float4 v = p4[q];
        r[4 * q + 0] = v.x; r[4 * q + 1] = v.y; r[4 * q + 2] = v.z; r[4 * q + 3] = v.w;
    }
}

__device__ __forceinline__ void store_row32(float* __restrict__ p, const float* __restrict__ r) {
    float4* p4 = reinterpret_cast<float4*>(p);
#pragma unroll
    for (int q = 0; q < 8; ++q) {
        float4 v;
        v.x = r[4 * q + 0]; v.y = r[4 * q + 1]; v.z = r[4 * q + 2]; v.w = r[4 * q + 3];
        p4[q] = v;
    }
}

// h_node row for node i from x[i] (W_in is [3,H])
__device__ __forceinline__ void hnode_row(const float* __restrict__ x, int i,
                                          const float* __restrict__ W_in,
                                          const float* __restrict__ b_in,
                                          float* __restrict__ r) {
    float x0 = x[(size_t)i * 3 + 0], x1 = x[(size_t)i * 3 + 1], x2 = x[(size_t)i * 3 + 2];
#pragma unroll
    for (int o = 0; o < H; ++o)
        r[o] = fmaf(x2, W_in[2 * H + o], fmaf(x1, W_in[1 * H + o], fmaf(x0, W_in[0 * H + o], b_in[o])));
}

// per-group segment scan over 32 staged LDS slots; lane owns one channel.
// Interior segments (start AND end observed) -> plain store (exclusively ours);
// first/last segments of the group -> atomicAdd into pre-zeroed table.
__device__ __forceinline__ void seg_scan32(const float* __restrict__ tile,
                                           const int* __restrict__ nid,
                                           int base, int lane,
                                           float* __restrict__ out) {
    int cur = nid[base];
    float acc = tile[base * LDS_STRIDE + lane];
    bool started = false;
#pragma unroll 4
    for (int j = 1; j < 32; ++j) {
        int n = nid[base + j];
        float v = tile[(base + j) * LDS_STRIDE + lane];
        if (n != cur) {
            if (started) out[(size_t)cur * H + lane] = acc;
            else atomicAdd(out + (size_t)cur * H + lane, acc);
            started = true;
            cur = n;
            acc = v;
        } else {
            acc += v;
        }
    }
    atomicAdd(out + (size_t)cur * H + lane, acc);   // last segment: end unknown
}

// 2-phase staged scan: 128-row LDS tile used twice (halves LDS -> 8 blocks/CU).
// Each thread's row m[] and dst are in registers; threads 0-127 use the tile
// first, then threads 128-255 reuse it.
__device__ __forceinline__ void staged_segsum_2phase(const float* __restrict__ m,
                                                     int dst, int tid,
                                                     float* __restrict__ tile,
                                                     int* __restrict__ nid,
                                                     float* __restrict__ out) {
    // phase A: rows 0-127
    if (tid < 128) {
        nid[tid] = dst;
#pragma unroll
        for (int o = 0; o < H; ++o) tile[tid * LDS_STRIDE + o] = m[o];
    }
    __syncthreads();
    if (tid < 128) seg_scan32(tile, nid, tid & ~31, tid & 31, out);
    __syncthreads();
    // phase B: rows 128-255 reuse the tile
    if (tid >= 128) {
        int r = tid - 128;
        nid[r] = dst;
#pragma unroll
        for (int o = 0; o < H; ++o) tile[r * LDS_STRIDE + o] = m[o];
    }
    __syncthreads();
    if (tid >= 128) seg_scan32(tile, nid, (tid - 128) & ~31, tid & 31, out);
}

// ---------------- fold: W2 = We@WN1top, Wfold = We@WN1bot, c1 = be@WN1top,
//                  c0 = bN1 + be@WN1bot ----------------
__global__ __launch_bounds__(1024) void fold_kernel(const float* __restrict__ We,
                                                    const float* __restrict__ be,
                                                    const float* __restrict__ WN1,
                                                    const float* __restrict__ bN1,
                                                    float* __restrict__ W2,
                                                    float* __restrict__ Wfold,
                                                    float* __restrict__ c1,
                                                    float* __restrict__ c0) {
    int t = threadIdx.x;
    int k = t >> 5, o = t & 31;
    float s2 = 0.0f, sf = 0.0f;
#pragma unroll
    for (int j = 0; j < H; ++j) {
        float w = We[k * H + j];
        s2 = fmaf(w, WN1[j * H + o], s2);
        sf = fmaf(w, WN1[(H + j) * H + o], sf);
    }
    W2[t] = s2;
    Wfold[t] = sf;
    if (k == 0) {
        float a = 0.0f, b = 0.0f;
#pragma unroll
        for (int j = 0; j < H; ++j) {
            a = fmaf(be[j], WN1[j * H + o], a);
            b = fmaf(be[j], WN1[(H + j) * H + o], b);
        }
        c1[o] = a;
        c0[o] = bN1[o] + b;
    }
}

// ---------------- utility zero kernels ----------------
__global__ __launch_bounds__(256) void zero_int_kernel(int* __restrict__ p, int n) {
    int i = blockIdx.x * blockDim.x + threadIdx.x;
    if (i < n) p[i] = 0;
}

__global__ __launch_bounds__(256) void zero_f4_kernel(float4* __restrict__ p, int n4) {
    int i = blockIdx.x * blockDim.x + threadIdx.x;
    if (i < n4) p[i] = make_float4(0.f, 0.f, 0.f, 0.f);
}

// ---------------- CSR build ----------------
__global__ __launch_bounds__(256) void hist_kernel(const int* __restrict__ eidx, int* __restrict__ cnt) {
    int e = blockIdx.x * blockDim.x + threadIdx.x;
    if (e >= N_EDGES) return;
    atomicAdd(&cnt[eidx[(size_t)N_EDGES + e]], 1);
}

__global__ __launch_bounds__(256) void scan_block_kernel(const int* __restrict__ cnt,
                                                         int* __restrict__ ptr,
                                                         int* __restrict__ bsum) {
    __shared__ int sm[256];
    int idx = blockIdx.x * 256 + threadIdx.x;
    int v = (idx < N_NODES) ? cnt[idx] : 0;
    sm[threadIdx.x] = v;
    __syncthreads();
    for (int off = 1; off < 256; off <<= 1) {
        int t = (threadIdx.x >= off) ? sm[threadIdx.x - off] : 0;
        __syncthreads();
        sm[threadIdx.x] += t;
        __syncthreads();
    }
    if (idx < N_NODES) ptr[idx] = sm[threadIdx.x] - v;   // exclusive within block
    if (threadIdx.x == 255) bsum[blockIdx.x] = sm[255];
}

__global__ __launch_bounds__(512) void scan_bsum_kernel(int* __restrict__ bsum, int nb) {
    __shared__ int sm[512];
    int v = (threadIdx.x < nb) ? bsum[threadIdx.x] : 0;
    sm[threadIdx.x] = v;
    __syncthreads();
    for (int off = 1; off < 512; off <<= 1) {
        int t = (threadIdx.x >= off) ? sm[threadIdx.x - off] : 0;
        __syncthreads();
        sm[threadIdx.x] += t;
        __syncthreads();
    }
    if (threadIdx.x < nb) bsum[threadIdx.x] = sm[threadIdx.x] - v;  // exclusive
}

__global__ __launch_bounds__(256) void scan_fix_kernel(int* __restrict__ ptr,
                                                       int* __restrict__ fill,
                                                       const int* __restrict__ bsum) {
    int idx = blockIdx.x * 256 + threadIdx.x;
    if (idx < N_NODES) {
        int p = ptr[idx] + bsum[blockIdx.x];
        ptr[idx] = p;
        fill[idx] = p;
    }
    if (idx == 0) ptr[N_NODES] = N_EDGES;
}

// scatter: slotmap[pos] = {edge id, dst node}
__global__ __launch_bounds__(256) void scatter_kernel(const int* __restrict__ eidx,
                                                      int* __restrict__ fill,
                                                      int2* __restrict__ slotmap) {
    int e = blockIdx.x * blockDim.x + threadIdx.x;
    if (e >= N_EDGES) return;
    int dst = eidx[(size_t)N_EDGES + e];
    int pos = atomicAdd(&fill[dst], 1);
    slotmap[pos] = make_int2(e, dst);
}

// ---------------- seg_sum1: LDS-staged segment sum of h_msg rows ----------------
__global__ __launch_bounds__(256) void seg_stage_kernel(const float* __restrict__ V,
                                                        const int2* __restrict__ slotmap,
                                                        float* __restrict__ out) {
    __shared__ float tile[128 * LDS_STRIDE];
    __shared__ int nid[128];
    int tid = threadIdx.x;
    int slot = blockIdx.x * 256 + tid;
    int2 sm = slotmap[slot];
    float m[H];
    load_row32(V + (size_t)sm.x * H, m);     // 8 independent b128 loads -> pipelined
    staged_segsum_2phase(m, sm.y, tid, tile, nid, out);
}

// ---------------- per-node: pre1 transform + N_node MLP -> pernode[n][64] ----------------
__global__ __launch_bounds__(256) void pernode_kernel(const float* __restrict__ x,
                                                      const float* __restrict__ raw,
                                                      const int* __restrict__ ptr,
                                                      const float* __restrict__ W_in,
                                                      const float* __restrict__ b_in,
                                                      const float* __restrict__ Wn1,
                                                      const float* __restrict__ bn1,
                                                      const float* __restrict__ Wn2,
                                                      const float* __restrict__ bn2,
                                                      const float* __restrict__ W2,
                                                      const float* __restrict__ c1,
                                                      const float* __restrict__ c0,
                                                      float* __restrict__ pernode) {
    int i = blockIdx.x * blockDim.x + threadIdx.x;
    if (i >= N_NODES) return;
    float s[H], p1[H];
    // pre1 = raw @ W2 + deg*c1 + c0
    load_row32(raw + (size_t)i * H, s);
    float deg = (float)(ptr[i + 1] - ptr[i]);
#pragma unroll
    for (int o = 0; o < H; ++o) p1[o] = fmaf(deg, c1[o], c0[o]);
    matvec32_acc(s, W2, p1);
    store_row32(pernode + (size_t)i * 64, p1);
    // nn = lrelu(lrelu(h_node@Wn1+bn1)@Wn2+bn2)
    hnode_row(x, i, W_in, b_in, s);
    matvec32(s, Wn1, bn1, p1);
#pragma unroll
    for (int o = 0; o < H; ++o) p1[o] = lrelu(p1[o]);
    matvec32(p1, Wn2, bn2, s);
#pragma unroll
    for (int o = 0; o < H; ++o) s[o] = lrelu(s[o]);
    store_row32(pernode + (size_t)i * 64 + 32, s);
}

// ---------------- fused pass2: per-edge MLP (slot order) + inline aggr_out ----------------
__global__ __launch_bounds__(256) void edge_fused_kernel(
    const float* __restrict__ h_msg, const int* __restrict__ eidx,
    const int2* __restrict__ slotmap,
    const float* __restrict__ pernode,
    const float* __restrict__ Wfold,
    const float* __restrict__ WN2, const float* __restrict__ bN2,
    const float* __restrict__ Wd, const float* __restrict__ bd,
    float* __restrict__ out_hmsg, float* __restrict__ out_ymsg,
    float* __restrict__ aggr_out) {
    __shared__ float tile[128 * LDS_STRIDE];
    __shared__ int nid[128];
    int tid = threadIdx.x;
    int slot = blockIdx.x * 256 + tid;      // grid exact (3.2M/256)
    int2 sm = slotmap[slot];
    int e = sm.x;
    int src = eidx[e];                       // src gather (12.8MB table, cache-resident)

    float m[H], t[H], u[H];

    // t = pre1[src] + h_msg[e] @ Wfold     (== cat_e @ WN1 + bN1)
    load_row32(h_msg + (size_t)e * H, m);
    load_row32(pernode + (size_t)src * 64, t);
    matvec32_acc(m, Wfold, t);
#pragma unroll
    for (int o = 0; o < H; ++o) t[o] = lrelu(t[o]);

    // u = t @ WN2 + bN2
    matvec32(t, WN2, bN2, u);

    // h_msg_new = nn_node[src] + lrelu(u)
    load_row32(pernode + (size_t)src * 64 + 32, t);
#pragma unroll
    for (int o = 0; o < H; ++o) m[o] = t[o] + lrelu(u[o]);

    store_row32(out_hmsg + (size_t)e * H, m);

    // y_msg = softmax(h_msg_new @ Wd + bd)
    float z0 = bd[0], z1 = bd[1];
#pragma unroll
    for (int k = 0; k < H; ++k) {
        z0 = fmaf(m[k], Wd[k * 2 + 0], z0);
        z1 = fmaf(m[k], Wd[k * 2 + 1], z1);
    }
    float zm = fmaxf(z0, z1);
    float e0 = __expf(z0 - zm), e1 = __expf(z1 - zm);
    float inv = 1.0f / (e0 + e1);
    *reinterpret_cast<float2*>(out_ymsg + (size_t)e * 2) = make_float2(e0 * inv, e1 * inv);

    // stage h_msg_new (2-phase LDS) and segment-sum into aggr_out
    staged_segsum_2phase(m, sm.y, tid, tile, nid, aggr_out);
}

// ---------------- node update + beliefs ----------------
__global__ __launch_bounds__(256) void node_update_kernel(
    const float* __restrict__ x, const float* __restrict__ aggr_out,
    const float* __restrict__ W_in, const float* __restrict__ b_in,
    const float* __restrict__ WU, const float* __restrict__ bU,
    const float* __restrict__ Wb, const float* __restrict__ bb,
    float* __restrict__ out_beliefs) {
    int i = blockIdx.x * blockDim.x + threadIdx.x;
    if (i >= N_NODES) return;
    float a[H], t[H];
    hnode_row(x, i, W_in, b_in, a);
    matvec32(a, WU, bU, t);
    load_row32(aggr_out + (size_t)i * H, a);
    matvec32_acc(a, WU + H * H, t);
#pragma unroll
    for (int o = 0; o < H; ++o) t[o] = lrelu(t[o]);

    // beliefs only for variable nodes (x[:,0]==1, contiguous prefix -> out row == i)
    if (x[(size_t)i * 3] == 1.0f) {
        float z0 = bb[0], z1 = bb[1];
#pragma unroll
        for (int k = 0; k < H; ++k) {
            z0 = fmaf(t[k], Wb[k * 2 + 0], z0);
            z1 = fmaf(t[k], Wb[k * 2 + 1], z1);
        }
        float zm = fmaxf(z0, z1);
        float e0 = __expf(z0 - zm), e1 = __expf(z1 - zm);
        float inv = 1.0f / (e0 + e1);
        out_beliefs[(size_t)i * 2 + 0] = e0 * inv;
        out_beliefs[(size_t)i * 2 + 1] = e1 * inv;
    }
}

extern "C" void kernel_launch(void* const* d_in, const int* in_sizes, int n_in,
                              void* d_out, int out_size, void* d_ws, size_t ws_size,
                              hipStream_t stream) {
    const float* x     = (const float*)d_in[0];
    const int*   eidx  = (const int*)d_in[1];
    const float* h_msg = (const float*)d_in[2];
    const float* W_in = (const float*)d_in[3];  const float* b_in = (const float*)d_in[4];
    const float* We   = (const float*)d_in[5];  const float* be   = (const float*)d_in[6];
    const float* Wn1  = (const float*)d_in[7];  const float* bn1  = (const float*)d_in[8];
    const float* Wn2  = (const float*)d_in[9];  const float* bn2  = (const float*)d_in[10];
    const float* WN1  = (const float*)d_in[11]; const float* bN1  = (const float*)d_in[12];
    const float* WN2  = (const float*)d_in[13]; const float* bN2  = (const float*)d_in[14];
    const float* WU   = (const float*)d_in[15]; const float* bU   = (const float*)d_in[16];
    const float* Wd   = (const float*)d_in[17]; const float* bd   = (const float*)d_in[18];
    const float* Wb   = (const float*)d_in[19]; const float* bb   = (const float*)d_in[20];

    float* out         = (float*)d_out;
    float* out_hmsg    = out;
    float* out_ymsg    = out + (size_t)N_EDGES * H;
    float* out_beliefs = out + (size_t)N_EDGES * (H + 2);

    // workspace layout (~65 MB)
    float* pernode = (float*)d_ws;                              // [N, 64] pre1|nn
    float* raw     = pernode + (size_t)N_NODES * 64;            // [N, H] h_msg sums, then aggr_out
    int2*  slotmap = (int2*)(raw + (size_t)N_NODES * H);        // [E] {edge, dst}
    float* W2      = (float*)(slotmap + N_EDGES);               // [H*H]
    float* Wfold   = W2 + H * H;                                // [H*H]
    float* c1      = Wfold + H * H;                             // [H]
    float* c0      = c1 + H;                                    // [H]
    int*   cnt     = (int*)(c0 + H);                            // [N]
    int*   ptr     = cnt + N_NODES;                             // [N+1]
    int*   fill    = ptr + (N_NODES + 1);                       // [N]
    int*   bsum    = fill + N_NODES;                            // [512]

    const int EB   = N_EDGES / 256;               // 12500 exact
    const int RAW4 = (N_NODES * H) / 4;           // float4 count for raw

    // --- folded weight matrices ---
    fold_kernel<<<1, 1024, 0, stream>>>(We, be, WN1, bN1, W2, Wfold, c1, c0);

    // --- CSR build (by dst) ---
    zero_int_kernel<<<SCAN_BLOCKS, 256, 0, stream>>>(cnt, N_NODES);
    hist_kernel<<<EB, 256, 0, stream>>>(eidx, cnt);
    scan_block_kernel<<<SCAN_BLOCKS, 256, 0, stream>>>(cnt, ptr, bsum);
    scan_bsum_kernel<<<1, 512, 0, stream>>>(bsum, SCAN_BLOCKS);
    scan_fix_kernel<<<SCAN_BLOCKS, 256, 0, stream>>>(ptr, fill, bsum);
    scatter_kernel<<<EB, 256, 0, stream>>>(eidx, fill, slotmap);

    // --- raw = segment_sum(h_msg, dst) ---
    zero_f4_kernel<<<(RAW4 + 255) / 256, 256, 0, stream>>>((float4*)raw, RAW4);
    seg_stage_kernel<<<EB, 256, 0, stream>>>(h_msg, slotmap, raw);

    // --- pernode: pre1 transform + nn_node ---
    pernode_kernel<<<SCAN_BLOCKS, 256, 0, stream>>>(
        x, raw, ptr, W_in, b_in, Wn1, bn1, Wn2, bn2, W2, c1, c0, pernode);

    // --- re-zero raw for aggr_out accumulation ---
    zero_f4_kernel<<<(RAW4 + 255) / 256, 256, 0, stream>>>((float4*)raw, RAW4);

    // --- fused: per-edge messages + inline segment_sum(h_msg_new) ---
    edge_fused_kernel<<<EB, 256, 0, stream>>>(
        h_msg, eidx, slotmap, pernode, Wfold, WN2, bN2, Wd, bd,
        out_hmsg, out_ymsg, raw);

    // --- node update + beliefs ---
    node_update_kernel<<<SCAN_BLOCKS, 256, 0, stream>>>(
        x, raw, W_in, b_in, WU, bU, Wb, bb, out_beliefs);
}

// Round 9
// 1118.456 us; speedup vs baseline: 1.0482x; 1.0482x over previous
//
#include <hip/hip_runtime.h>
#include <hip/hip_fp16.h>
#include <math.h>

#define N_NODES 100000
#define N_EDGES 3200000
#define H 32
#define SCAN_BLOCKS ((N_NODES + 255) / 256)   // 391
#define HSTRIDE 34                            // fp16 tile stride: tid*17 mod 32 distinct -> conflict-free

__device__ __forceinline__ float lrelu(float v) { return v > 0.0f ? v : 0.01f * v; }

// out = bias + in @ W   (W is [H,H] row-major: W[k*H+o]); uniform W/bias -> s_loads
__device__ __forceinline__ void matvec32(const float* __restrict__ in,
                                         const float* __restrict__ W,
                                         const float* __restrict__ bias,
                                         float* __restrict__ out) {
#pragma unroll
    for (int o = 0; o < H; ++o) out[o] = bias[o];
#pragma unroll
    for (int k = 0; k < H; ++k) {
        float v = in[k];
#pragma unroll
        for (int o = 0; o < H; ++o) out[o] = fmaf(v, W[k * H + o], out[o]);
    }
}

// out += in @ W
__device__ __forceinline__ void matvec32_acc(const float* __restrict__ in,
                                             const float* __restrict__ W,
                                             float* __restrict__ out) {
#pragma unroll
    for (int k = 0; k < H; ++k) {
        float v = in[k];
#pragma unroll
        for (int o = 0; o < H; ++o) out[o] = fmaf(v, W[k * H + o], out[o]);
    }
}

__device__ __forceinline__ void load_row32(const float* __restrict__ p, float* __restrict__ r) {
    const float4* p4 = reinterpret_cast<const float4*>(p);
#pragma unroll
    for (int q = 0; q < 8; ++q) {
        float4 v = p4[q];
        r[4 * q + 0] = v.x; r[4 * q + 1] = v.y; r[4 * q + 2] = v.z; r[4 * q + 3] = v.w;
    }
}

__device__ __forceinline__ void store_row32(float* __restrict__ p, const float* __restrict__ r) {
    float4* p4 = reinterpret_cast<float4*>(p);
#pragma unroll
    for (int q = 0; q < 8; ++q) {
        float4 v;
        v.x = r[4 * q + 0]; v.y = r[4 * q + 1]; v.z = r[4 * q + 2]; v.w = r[4 * q + 3];
        p4[q] = v;
    }
}

// 32 fp16 -> 32 f32 (p must be 4B-aligned; 128B-aligned rows vectorize to b128)
__device__ __forceinline__ void load_row32_h(const __half2* __restrict__ p, float* __restrict__ r) {
#pragma unroll
    for (int q = 0; q < 16; ++q) {
        float2 f = __half22float2(p[q]);
        r[2 * q + 0] = f.x; r[2 * q + 1] = f.y;
    }
}

__device__ __forceinline__ void store_row32_h(__half2* __restrict__ p, const float* __restrict__ r) {
#pragma unroll
    for (int q = 0; q < 16; ++q) p[q] = __floats2half2_rn(r[2 * q], r[2 * q + 1]);
}

// h_node row for node i from x[i] (W_in is [3,H])
__device__ __forceinline__ void hnode_row(const float* __restrict__ x, int i,
                                          const float* __restrict__ W_in,
                                          const float* __restrict__ b_in,
                                          float* __restrict__ r) {
    float x0 = x[(size_t)i * 3 + 0], x1 = x[(size_t)i * 3 + 1], x2 = x[(size_t)i * 3 + 2];
#pragma unroll
    for (int o = 0; o < H; ++o)
        r[o] = fmaf(x2, W_in[2 * H + o], fmaf(x1, W_in[1 * H + o], fmaf(x0, W_in[0 * H + o], b_in[o])));
}

// per-group segment scan over 32 staged fp16 LDS slots; lane owns one channel.
// Interior segments -> plain store; group-boundary segments -> atomicAdd (pre-zeroed out).
__device__ __forceinline__ void seg_scan32_h(const __half* __restrict__ tile,
                                             const int* __restrict__ nid,
                                             int base, int lane,
                                             float* __restrict__ out) {
    int cur = nid[base];
    float acc = __half2float(tile[base * HSTRIDE + lane]);
    bool started = false;
#pragma unroll 4
    for (int j = 1; j < 32; ++j) {
        int n = nid[base + j];
        float v = __half2float(tile[(base + j) * HSTRIDE + lane]);
        if (n != cur) {
            if (started) out[(size_t)cur * H + lane] = acc;
            else atomicAdd(out + (size_t)cur * H + lane, acc);
            started = true;
            cur = n;
            acc = v;
        } else {
            acc += v;
        }
    }
    atomicAdd(out + (size_t)cur * H + lane, acc);   // last segment: end unknown
}

// stage row (fp16) + dst, then scan (single-phase, 256 rows)
__device__ __forceinline__ void staged_segsum(const float* __restrict__ m,
                                              int dst, int tid,
                                              __half* __restrict__ tile,
                                              int* __restrict__ nid,
                                              float* __restrict__ out) {
    nid[tid] = dst;
    __half2* row = reinterpret_cast<__half2*>(tile + tid * HSTRIDE);
#pragma unroll
    for (int q = 0; q < 16; ++q) row[q] = __floats2half2_rn(m[2 * q], m[2 * q + 1]);
    __syncthreads();
    seg_scan32_h(tile, nid, tid & ~31, tid & 31, out);
}

// ---------------- fold: W2 = We@WN1top, Wfold = We@WN1bot, c1 = be@WN1top,
//                  c0 = bN1 + be@WN1bot ----------------
__global__ __launch_bounds__(1024) void fold_kernel(const float* __restrict__ We,
                                                    const float* __restrict__ be,
                                                    const float* __restrict__ WN1,
                                                    const float* __restrict__ bN1,
                                                    float* __restrict__ W2,
                                                    float* __restrict__ Wfold,
                                                    float* __restrict__ c1,
                                                    float* __restrict__ c0) {
    int t = threadIdx.x;
    int k = t >> 5, o = t & 31;
    float s2 = 0.0f, sf = 0.0f;
#pragma unroll
    for (int j = 0; j < H; ++j) {
        float w = We[k * H + j];
        s2 = fmaf(w, WN1[j * H + o], s2);
        sf = fmaf(w, WN1[(H + j) * H + o], sf);
    }
    W2[t] = s2;
    Wfold[t] = sf;
    if (k == 0) {
        float a = 0.0f, b = 0.0f;
#pragma unroll
        for (int j = 0; j < H; ++j) {
            a = fmaf(be[j], WN1[j * H + o], a);
            b = fmaf(be[j], WN1[(H + j) * H + o], b);
        }
        c1[o] = a;
        c0[o] = bN1[o] + b;
    }
}

// ---------------- utility zero kernels ----------------
__global__ __launch_bounds__(256) void zero_int_kernel(int* __restrict__ p, int n) {
    int i = blockIdx.x * blockDim.x + threadIdx.x;
    if (i < n) p[i] = 0;
}

__global__ __launch_bounds__(256) void zero_f4_kernel(float4* __restrict__ p, int n4) {
    int i = blockIdx.x * blockDim.x + threadIdx.x;
    if (i < n4) p[i] = make_float4(0.f, 0.f, 0.f, 0.f);
}

// ---------------- CSR build ----------------
__global__ __launch_bounds__(256) void hist_kernel(const int* __restrict__ eidx, int* __restrict__ cnt) {
    int e = blockIdx.x * blockDim.x + threadIdx.x;
    if (e >= N_EDGES) return;
    atomicAdd(&cnt[eidx[(size_t)N_EDGES + e]], 1);
}

__global__ __launch_bounds__(256) void scan_block_kernel(const int* __restrict__ cnt,
                                                         int* __restrict__ ptr,
                                                         int* __restrict__ bsum) {
    __shared__ int sm[256];
    int idx = blockIdx.x * 256 + threadIdx.x;
    int v = (idx < N_NODES) ? cnt[idx] : 0;
    sm[threadIdx.x] = v;
    __syncthreads();
    for (int off = 1; off < 256; off <<= 1) {
        int t = (threadIdx.x >= off) ? sm[threadIdx.x - off] : 0;
        __syncthreads();
        sm[threadIdx.x] += t;
        __syncthreads();
    }
    if (idx < N_NODES) ptr[idx] = sm[threadIdx.x] - v;   // exclusive within block
    if (threadIdx.x == 255) bsum[blockIdx.x] = sm[255];
}

__global__ __launch_bounds__(512) void scan_bsum_kernel(int* __restrict__ bsum, int nb) {
    __shared__ int sm[512];
    int v = (threadIdx.x < nb) ? bsum[threadIdx.x] : 0;
    sm[threadIdx.x] = v;
    __syncthreads();
    for (int off = 1; off < 512; off <<= 1) {
        int t = (threadIdx.x >= off) ? sm[threadIdx.x - off] : 0;
        __syncthreads();
        sm[threadIdx.x] += t;
        __syncthreads();
    }
    if (threadIdx.x < nb) bsum[threadIdx.x] = sm[threadIdx.x] - v;  // exclusive
}

__global__ __launch_bounds__(256) void scan_fix_kernel(int* __restrict__ ptr,
                                                       int* __restrict__ fill,
                                                       const int* __restrict__ bsum) {
    int idx = blockIdx.x * 256 + threadIdx.x;
    if (idx < N_NODES) {
        int p = ptr[idx] + bsum[blockIdx.x];
        ptr[idx] = p;
        fill[idx] = p;
    }
    if (idx == 0) ptr[N_NODES] = N_EDGES;
}

// scatter: slotmap[pos] = {edge id, dst node}
__global__ __launch_bounds__(256) void scatter_kernel(const int* __restrict__ eidx,
                                                      int* __restrict__ fill,
                                                      int2* __restrict__ slotmap) {
    int e = blockIdx.x * blockDim.x + threadIdx.x;
    if (e >= N_EDGES) return;
    int dst = eidx[(size_t)N_EDGES + e];
    int pos = atomicAdd(&fill[dst], 1);
    slotmap[pos] = make_int2(e, dst);
}

// ---------------- seg_sum1: LDS-staged segment sum of h_msg rows ----------------
__global__ __launch_bounds__(256) void seg_stage_kernel(const float* __restrict__ V,
                                                        const int2* __restrict__ slotmap,
                                                        float* __restrict__ out) {
    __shared__ __half tile[256 * HSTRIDE];
    __shared__ int nid[256];
    int tid = threadIdx.x;
    int slot = blockIdx.x * 256 + tid;
    int2 sm = slotmap[slot];
    float m[H];
    load_row32(V + (size_t)sm.x * H, m);     // 8 independent b128 loads -> pipelined
    staged_segsum(m, sm.y, tid, tile, nid, out);
}

// ---------------- per-node: pre1 transform + N_node MLP -> fp16 pernode[n][64] ----------------
__global__ __launch_bounds__(256) void pernode_kernel(const float* __restrict__ x,
                                                      const float* __restrict__ raw,
                                                      const int* __restrict__ ptr,
                                                      const float* __restrict__ W_in,
                                                      const float* __restrict__ b_in,
                                                      const float* __restrict__ Wn1,
                                                      const float* __restrict__ bn1,
                                                      const float* __restrict__ Wn2,
                                                      const float* __restrict__ bn2,
                                                      const float* __restrict__ W2,
                                                      const float* __restrict__ c1,
                                                      const float* __restrict__ c0,
                                                      __half* __restrict__ pernode) {
    int i = blockIdx.x * blockDim.x + threadIdx.x;
    if (i >= N_NODES) return;
    float s[H], p1[H];
    __half2* row = reinterpret_cast<__half2*>(pernode + (size_t)i * 64);
    // pre1 = raw @ W2 + deg*c1 + c0
    load_row32(raw + (size_t)i * H, s);
    float deg = (float)(ptr[i + 1] - ptr[i]);
#pragma unroll
    for (int o = 0; o < H; ++o) p1[o] = fmaf(deg, c1[o], c0[o]);
    matvec32_acc(s, W2, p1);
    store_row32_h(row, p1);
    // nn = lrelu(lrelu(h_node@Wn1+bn1)@Wn2+bn2)
    hnode_row(x, i, W_in, b_in, s);
    matvec32(s, Wn1, bn1, p1);
#pragma unroll
    for (int o = 0; o < H; ++o) p1[o] = lrelu(p1[o]);
    matvec32(p1, Wn2, bn2, s);
#pragma unroll
    for (int o = 0; o < H; ++o) s[o] = lrelu(s[o]);
    store_row32_h(row + 16, s);
}

// ---------------- fused pass2: per-edge MLP (slot order) + inline aggr_out ----------------
__global__ __launch_bounds__(256) void edge_fused_kernel(
    const float* __restrict__ h_msg, const int* __restrict__ eidx,
    const int2* __restrict__ slotmap,
    const __half* __restrict__ pernode,
    const float* __restrict__ Wfold,
    const float* __restrict__ WN2, const float* __restrict__ bN2,
    const float* __restrict__ Wd, const float* __restrict__ bd,
    float* __restrict__ out_hmsg, float* __restrict__ out_ymsg,
    float* __restrict__ aggr_out) {
    __shared__ __half tile[256 * HSTRIDE];
    __shared__ int nid[256];
    int tid = threadIdx.x;
    int slot = blockIdx.x * 256 + tid;      // grid exact (3.2M/256)
    int2 sm = slotmap[slot];
    int e = sm.x;
    int src = eidx[e];                       // src gather (12.8MB table, cache-resident)

    float m[H], t[H], u[H];
    const __half2* pn = reinterpret_cast<const __half2*>(pernode + (size_t)src * 64);

    // t = pre1[src] + h_msg[e] @ Wfold     (== cat_e @ WN1 + bN1)
    load_row32(h_msg + (size_t)e * H, m);
    load_row32_h(pn, t);
    matvec32_acc(m, Wfold, t);
#pragma unroll
    for (int o = 0; o < H; ++o) t[o] = lrelu(t[o]);

    // u = t @ WN2 + bN2
    matvec32(t, WN2, bN2, u);

    // h_msg_new = nn_node[src] + lrelu(u)
    load_row32_h(pn + 16, t);
#pragma unroll
    for (int o = 0; o < H; ++o) m[o] = t[o] + lrelu(u[o]);

    store_row32(out_hmsg + (size_t)e * H, m);

    // y_msg = softmax(h_msg_new @ Wd + bd)
    float z0 = bd[0], z1 = bd[1];
#pragma unroll
    for (int k = 0; k < H; ++k) {
        z0 = fmaf(m[k], Wd[k * 2 + 0], z0);
        z1 = fmaf(m[k], Wd[k * 2 + 1], z1);
    }
    float zm = fmaxf(z0, z1);
    float e0 = __expf(z0 - zm), e1 = __expf(z1 - zm);
    float inv = 1.0f / (e0 + e1);
    *reinterpret_cast<float2*>(out_ymsg + (size_t)e * 2) = make_float2(e0 * inv, e1 * inv);

    // stage h_msg_new (fp16 LDS) and segment-sum into aggr_out
    staged_segsum(m, sm.y, tid, tile, nid, aggr_out);
}

// ---------------- node update + beliefs ----------------
__global__ __launch_bounds__(256) void node_update_kernel(
    const float* __restrict__ x, const float* __restrict__ aggr_out,
    const float* __restrict__ W_in, const float* __restrict__ b_in,
    const float* __restrict__ WU, const float* __restrict__ bU,
    const float* __restrict__ Wb, const float* __restrict__ bb,
    float* __restrict__ out_beliefs) {
    int i = blockIdx.x * blockDim.x + threadIdx.x;
    if (i >= N_NODES) return;
    float a[H], t[H];
    hnode_row(x, i, W_in, b_in, a);
    matvec32(a, WU, bU, t);
    load_row32(aggr_out + (size_t)i * H, a);
    matvec32_acc(a, WU + H * H, t);
#pragma unroll
    for (int o = 0; o < H; ++o) t[o] = lrelu(t[o]);

    // beliefs only for variable nodes (x[:,0]==1, contiguous prefix -> out row == i)
    if (x[(size_t)i * 3] == 1.0f) {
        float z0 = bb[0], z1 = bb[1];
#pragma unroll
        for (int k = 0; k < H; ++k) {
            z0 = fmaf(t[k], Wb[k * 2 + 0], z0);
            z1 = fmaf(t[k], Wb[k * 2 + 1], z1);
        }
        float zm = fmaxf(z0, z1);
        float e0 = __expf(z0 - zm), e1 = __expf(z1 - zm);
        float inv = 1.0f / (e0 + e1);
        out_beliefs[(size_t)i * 2 + 0] = e0 * inv;
        out_beliefs[(size_t)i * 2 + 1] = e1 * inv;
    }
}

extern "C" void kernel_launch(void* const* d_in, const int* in_sizes, int n_in,
                              void* d_out, int out_size, void* d_ws, size_t ws_size,
                              hipStream_t stream) {
    const float* x     = (const float*)d_in[0];
    const int*   eidx  = (const int*)d_in[1];
    const float* h_msg = (const float*)d_in[2];
    const float* W_in = (const float*)d_in[3];  const float* b_in = (const float*)d_in[4];
    const float* We   = (const float*)d_in[5];  const float* be   = (const float*)d_in[6];
    const float* Wn1  = (const float*)d_in[7];  const float* bn1  = (const float*)d_in[8];
    const float* Wn2  = (const float*)d_in[9];  const float* bn2  = (const float*)d_in[10];
    const float* WN1  = (const float*)d_in[11]; const float* bN1  = (const float*)d_in[12];
    const float* WN2  = (const float*)d_in[13]; const float* bN2  = (const float*)d_in[14];
    const float* WU   = (const float*)d_in[15]; const float* bU   = (const float*)d_in[16];
    const float* Wd   = (const float*)d_in[17]; const float* bd   = (const float*)d_in[18];
    const float* Wb   = (const float*)d_in[19]; const float* bb   = (const float*)d_in[20];

    float* out         = (float*)d_out;
    float* out_hmsg    = out;
    float* out_ymsg    = out + (size_t)N_EDGES * H;
    float* out_beliefs = out + (size_t)N_EDGES * (H + 2);

    // workspace layout (~52 MB)
    __half* pernode = (__half*)d_ws;                            // [N, 64] fp16 pre1|nn
    float*  raw     = (float*)(pernode + (size_t)N_NODES * 64); // [N, H] h_msg sums, then aggr_out
    int2*   slotmap = (int2*)(raw + (size_t)N_NODES * H);       // [E] {edge, dst}
    float*  W2      = (float*)(slotmap + N_EDGES);              // [H*H]
    float*  Wfold   = W2 + H * H;                               // [H*H]
    float*  c1      = Wfold + H * H;                            // [H]
    float*  c0      = c1 + H;                                   // [H]
    int*    cnt     = (int*)(c0 + H);                           // [N]
    int*    ptr     = cnt + N_NODES;                            // [N+1]
    int*    fill    = ptr + (N_NODES + 1);                      // [N]
    int*    bsum    = fill + N_NODES;                           // [512]

    const int EB   = N_EDGES / 256;               // 12500 exact
    const int RAW4 = (N_NODES * H) / 4;           // float4 count for raw

    // --- folded weight matrices ---
    fold_kernel<<<1, 1024, 0, stream>>>(We, be, WN1, bN1, W2, Wfold, c1, c0);

    // --- CSR build (by dst) ---
    zero_int_kernel<<<SCAN_BLOCKS, 256, 0, stream>>>(cnt, N_NODES);
    hist_kernel<<<EB, 256, 0, stream>>>(eidx, cnt);
    scan_block_kernel<<<SCAN_BLOCKS, 256, 0, stream>>>(cnt, ptr, bsum);
    scan_bsum_kernel<<<1, 512, 0, stream>>>(bsum, SCAN_BLOCKS);
    scan_fix_kernel<<<SCAN_BLOCKS, 256, 0, stream>>>(ptr, fill, bsum);
    scatter_kernel<<<EB, 256, 0, stream>>>(eidx, fill, slotmap);

    // --- raw = segment_sum(h_msg, dst) ---
    zero_f4_kernel<<<(RAW4 + 255) / 256, 256, 0, stream>>>((float4*)raw, RAW4);
    seg_stage_kernel<<<EB, 256, 0, stream>>>(h_msg, slotmap, raw);

    // --- pernode: pre1 transform + nn_node (fp16) ---
    pernode_kernel<<<SCAN_BLOCKS, 256, 0, stream>>>(
        x, raw, ptr, W_in, b_in, Wn1, bn1, Wn2, bn2, W2, c1, c0, pernode);

    // --- re-zero raw for aggr_out accumulation ---
    zero_f4_kernel<<<(RAW4 + 255) / 256, 256, 0, stream>>>((float4*)raw, RAW4);

    // --- fused: per-edge messages + inline segment_sum(h_msg_new) ---
    edge_fused_kernel<<<EB, 256, 0, stream>>>(
        h_msg, eidx, slotmap, pernode, Wfold, WN2, bN2, Wd, bd,
        out_hmsg, out_ymsg, raw);

    // --- node update + beliefs ---
    node_update_kernel<<<SCAN_BLOCKS, 256, 0, stream>>>(
        x, raw, W_in, b_in, WU, bU, Wb, bb, out_beliefs);
}

// Round 10
// 909.554 us; speedup vs baseline: 1.2889x; 1.2297x over previous
//
#include <hip/hip_runtime.h>
#include <hip/hip_fp16.h>
#include <math.h>

#define N_NODES 100000
#define N_EDGES 3200000
#define H 32
#define SCAN_BLOCKS ((N_NODES + 255) / 256)   // 391
#define HSTRIDE 34                            // fp16 tile stride (conflict-free)

__device__ __forceinline__ float lrelu(float v) { return v > 0.0f ? v : 0.01f * v; }

__device__ __forceinline__ void matvec32(const float* __restrict__ in,
                                         const float* __restrict__ W,
                                         const float* __restrict__ bias,
                                         float* __restrict__ out) {
#pragma unroll
    for (int o = 0; o < H; ++o) out[o] = bias[o];
#pragma unroll
    for (int k = 0; k < H; ++k) {
        float v = in[k];
#pragma unroll
        for (int o = 0; o < H; ++o) out[o] = fmaf(v, W[k * H + o], out[o]);
    }
}

__device__ __forceinline__ void matvec32_acc(const float* __restrict__ in,
                                             const float* __restrict__ W,
                                             float* __restrict__ out) {
#pragma unroll
    for (int k = 0; k < H; ++k) {
        float v = in[k];
#pragma unroll
        for (int o = 0; o < H; ++o) out[o] = fmaf(v, W[k * H + o], out[o]);
    }
}

__device__ __forceinline__ void load_row32(const float* __restrict__ p, float* __restrict__ r) {
    const float4* p4 = reinterpret_cast<const float4*>(p);
#pragma unroll
    for (int q = 0; q < 8; ++q) {
        float4 v = p4[q];
        r[4 * q + 0] = v.x; r[4 * q + 1] = v.y; r[4 * q + 2] = v.z; r[4 * q + 3] = v.w;
    }
}

__device__ __forceinline__ void store_row32(float* __restrict__ p, const float* __restrict__ r) {
    float4* p4 = reinterpret_cast<float4*>(p);
#pragma unroll
    for (int q = 0; q < 8; ++q) {
        float4 v;
        v.x = r[4 * q + 0]; v.y = r[4 * q + 1]; v.z = r[4 * q + 2]; v.w = r[4 * q + 3];
        p4[q] = v;
    }
}

__device__ __forceinline__ void load_row32_h(const __half2* __restrict__ p, float* __restrict__ r) {
#pragma unroll
    for (int q = 0; q < 16; ++q) {
        float2 f = __half22float2(p[q]);
        r[2 * q + 0] = f.x; r[2 * q + 1] = f.y;
    }
}

__device__ __forceinline__ void store_row32_h(__half2* __restrict__ p, const float* __restrict__ r) {
#pragma unroll
    for (int q = 0; q < 16; ++q) p[q] = __floats2half2_rn(r[2 * q], r[2 * q + 1]);
}

__device__ __forceinline__ void hnode_row(const float* __restrict__ x, int i,
                                          const float* __restrict__ W_in,
                                          const float* __restrict__ b_in,
                                          float* __restrict__ r) {
    float x0 = x[(size_t)i * 3 + 0], x1 = x[(size_t)i * 3 + 1], x2 = x[(size_t)i * 3 + 2];
#pragma unroll
    for (int o = 0; o < H; ++o)
        r[o] = fmaf(x2, W_in[2 * H + o], fmaf(x1, W_in[1 * H + o], fmaf(x0, W_in[0 * H + o], b_in[o])));
}

// per-group segment scan over 32 staged fp16 LDS slots; lane owns one channel.
__device__ __forceinline__ void seg_scan32_h(const __half* __restrict__ tile,
                                             const int* __restrict__ nid,
                                             int base, int lane,
                                             float* __restrict__ out) {
    int cur = nid[base];
    float acc = __half2float(tile[base * HSTRIDE + lane]);
    bool started = false;
#pragma unroll 4
    for (int j = 1; j < 32; ++j) {
        int n = nid[base + j];
        float v = __half2float(tile[(base + j) * HSTRIDE + lane]);
        if (n != cur) {
            if (started) out[(size_t)cur * H + lane] = acc;
            else atomicAdd(out + (size_t)cur * H + lane, acc);
            started = true;
            cur = n;
            acc = v;
        } else {
            acc += v;
        }
    }
    atomicAdd(out + (size_t)cur * H + lane, acc);
}

__device__ __forceinline__ void staged_segsum(const float* __restrict__ m,
                                              int dst, int tid,
                                              __half* __restrict__ tile,
                                              int* __restrict__ nid,
                                              float* __restrict__ out) {
    nid[tid] = dst;
    __half2* row = reinterpret_cast<__half2*>(tile + tid * HSTRIDE);
#pragma unroll
    for (int q = 0; q < 16; ++q) row[q] = __floats2half2_rn(m[2 * q], m[2 * q + 1]);
    __syncthreads();
    seg_scan32_h(tile, nid, tid & ~31, tid & 31, out);
}

// ---------------- fold ----------------
__global__ __launch_bounds__(1024) void fold_kernel(const float* __restrict__ We,
                                                    const float* __restrict__ be,
                                                    const float* __restrict__ WN1,
                                                    const float* __restrict__ bN1,
                                                    float* __restrict__ W2,
                                                    float* __restrict__ Wfold,
                                                    float* __restrict__ c1,
                                                    float* __restrict__ c0) {
    int t = threadIdx.x;
    int k = t >> 5, o = t & 31;
    float s2 = 0.0f, sf = 0.0f;
#pragma unroll
    for (int j = 0; j < H; ++j) {
        float w = We[k * H + j];
        s2 = fmaf(w, WN1[j * H + o], s2);
        sf = fmaf(w, WN1[(H + j) * H + o], sf);
    }
    W2[t] = s2;
    Wfold[t] = sf;
    if (k == 0) {
        float a = 0.0f, b = 0.0f;
#pragma unroll
        for (int j = 0; j < H; ++j) {
            a = fmaf(be[j], WN1[j * H + o], a);
            b = fmaf(be[j], WN1[(H + j) * H + o], b);
        }
        c1[o] = a;
        c0[o] = bN1[o] + b;
    }
}

// ---------------- utility ----------------
__global__ __launch_bounds__(256) void zero_int_kernel(int* __restrict__ p, int n) {
    int i = blockIdx.x * blockDim.x + threadIdx.x;
    if (i < n) p[i] = 0;
}

__global__ __launch_bounds__(256) void zero_f4_kernel(float4* __restrict__ p, int n4) {
    int i = blockIdx.x * blockDim.x + threadIdx.x;
    if (i < n4) p[i] = make_float4(0.f, 0.f, 0.f, 0.f);
}

// ---------------- CSR build ----------------
__global__ __launch_bounds__(256) void hist_kernel(const int* __restrict__ eidx, int* __restrict__ cnt) {
    int e = blockIdx.x * blockDim.x + threadIdx.x;
    if (e >= N_EDGES) return;
    atomicAdd(&cnt[eidx[(size_t)N_EDGES + e]], 1);
}

__global__ __launch_bounds__(256) void scan_block_kernel(const int* __restrict__ cnt,
                                                         int* __restrict__ ptr,
                                                         int* __restrict__ bsum) {
    __shared__ int sm[256];
    int idx = blockIdx.x * 256 + threadIdx.x;
    int v = (idx < N_NODES) ? cnt[idx] : 0;
    sm[threadIdx.x] = v;
    __syncthreads();
    for (int off = 1; off < 256; off <<= 1) {
        int t = (threadIdx.x >= off) ? sm[threadIdx.x - off] : 0;
        __syncthreads();
        sm[threadIdx.x] += t;
        __syncthreads();
    }
    if (idx < N_NODES) ptr[idx] = sm[threadIdx.x] - v;
    if (threadIdx.x == 255) bsum[blockIdx.x] = sm[255];
}

__global__ __launch_bounds__(512) void scan_bsum_kernel(int* __restrict__ bsum, int nb) {
    __shared__ int sm[512];
    int v = (threadIdx.x < nb) ? bsum[threadIdx.x] : 0;
    sm[threadIdx.x] = v;
    __syncthreads();
    for (int off = 1; off < 512; off <<= 1) {
        int t = (threadIdx.x >= off) ? sm[threadIdx.x - off] : 0;
        __syncthreads();
        sm[threadIdx.x] += t;
        __syncthreads();
    }
    if (threadIdx.x < nb) bsum[threadIdx.x] = sm[threadIdx.x] - v;
}

__global__ __launch_bounds__(256) void scan_fix_kernel(int* __restrict__ ptr,
                                                       int* __restrict__ fill,
                                                       const int* __restrict__ bsum) {
    int idx = blockIdx.x * 256 + threadIdx.x;
    if (idx < N_NODES) {
        int p = ptr[idx] + bsum[blockIdx.x];
        ptr[idx] = p;
        fill[idx] = p;
    }
    if (idx == 0) ptr[N_NODES] = N_EDGES;
}

// ======== PATH A (big ws): scatter materializes slot-sorted fp16 h_msg ========
__global__ __launch_bounds__(256) void scatter_big_kernel(const int* __restrict__ eidx,
                                                          const float* __restrict__ h_msg,
                                                          int* __restrict__ fill,
                                                          int4* __restrict__ slotmap4,
                                                          __half* __restrict__ hs) {
    int e = blockIdx.x * blockDim.x + threadIdx.x;
    if (e >= N_EDGES) return;
    int src = eidx[e];
    int dst = eidx[(size_t)N_EDGES + e];
    float m[H];
    load_row32(h_msg + (size_t)e * H, m);          // sequential 128B read
    int pos = atomicAdd(&fill[dst], 1);
    slotmap4[pos] = make_int4(e, dst, src, 0);     // one 16B random write
    store_row32_h(reinterpret_cast<__half2*>(hs + (size_t)pos * H), m); // one 64B sector
}

__global__ __launch_bounds__(256) void seg_stage_big_kernel(const __half* __restrict__ hs,
                                                            const int4* __restrict__ slotmap4,
                                                            float* __restrict__ out) {
    __shared__ __half tile[256 * HSTRIDE];
    __shared__ int nid[256];
    int tid = threadIdx.x;
    int slot = blockIdx.x * 256 + tid;
    nid[tid] = slotmap4[slot].y;
    const __half2* row = reinterpret_cast<const __half2*>(hs + (size_t)slot * H);  // sequential
    __half2* trow = reinterpret_cast<__half2*>(tile + tid * HSTRIDE);
#pragma unroll
    for (int q = 0; q < 16; ++q) trow[q] = row[q];
    __syncthreads();
    seg_scan32_h(tile, nid, tid & ~31, tid & 31, out);
}

__global__ __launch_bounds__(256) void edge_fused_big_kernel(
    const __half* __restrict__ hs, const int4* __restrict__ slotmap4,
    const __half* __restrict__ pernode,
    const float* __restrict__ Wfold,
    const float* __restrict__ WN2, const float* __restrict__ bN2,
    const float* __restrict__ Wd, const float* __restrict__ bd,
    float* __restrict__ out_hmsg, float* __restrict__ out_ymsg,
    float* __restrict__ aggr_out) {
    __shared__ __half tile[256 * HSTRIDE];
    __shared__ int nid[256];
    int tid = threadIdx.x;
    int slot = blockIdx.x * 256 + tid;
    int4 sm = slotmap4[slot];                      // sequential 16B
    int e = sm.x, dst = sm.y, src = sm.z;

    float m[H], t[H], u[H];
    const __half2* pn = reinterpret_cast<const __half2*>(pernode + (size_t)src * 64);

    load_row32_h(reinterpret_cast<const __half2*>(hs + (size_t)slot * H), m);  // sequential
    load_row32_h(pn, t);                           // the one remaining random gather
    matvec32_acc(m, Wfold, t);
#pragma unroll
    for (int o = 0; o < H; ++o) t[o] = lrelu(t[o]);

    matvec32(t, WN2, bN2, u);

    load_row32_h(pn + 16, t);
#pragma unroll
    for (int o = 0; o < H; ++o) m[o] = t[o] + lrelu(u[o]);

    store_row32(out_hmsg + (size_t)e * H, m);

    float z0 = bd[0], z1 = bd[1];
#pragma unroll
    for (int k = 0; k < H; ++k) {
        z0 = fmaf(m[k], Wd[k * 2 + 0], z0);
        z1 = fmaf(m[k], Wd[k * 2 + 1], z1);
    }
    float zm = fmaxf(z0, z1);
    float e0 = __expf(z0 - zm), e1 = __expf(z1 - zm);
    float inv = 1.0f / (e0 + e1);
    *reinterpret_cast<float2*>(out_ymsg + (size_t)e * 2) = make_float2(e0 * inv, e1 * inv);

    staged_segsum(m, dst, tid, tile, nid, aggr_out);
}

// ======== PATH B (fallback, round-9 proven) ========
__global__ __launch_bounds__(256) void scatter_kernel(const int* __restrict__ eidx,
                                                      int* __restrict__ fill,
                                                      int2* __restrict__ slotmap) {
    int e = blockIdx.x * blockDim.x + threadIdx.x;
    if (e >= N_EDGES) return;
    int dst = eidx[(size_t)N_EDGES + e];
    int pos = atomicAdd(&fill[dst], 1);
    slotmap[pos] = make_int2(e, dst);
}

__global__ __launch_bounds__(256) void seg_stage_kernel(const float* __restrict__ V,
                                                        const int2* __restrict__ slotmap,
                                                        float* __restrict__ out) {
    __shared__ __half tile[256 * HSTRIDE];
    __shared__ int nid[256];
    int tid = threadIdx.x;
    int slot = blockIdx.x * 256 + tid;
    int2 sm = slotmap[slot];
    float m[H];
    load_row32(V + (size_t)sm.x * H, m);
    staged_segsum(m, sm.y, tid, tile, nid, out);
}

__global__ __launch_bounds__(256) void edge_fused_kernel(
    const float* __restrict__ h_msg, const int* __restrict__ eidx,
    const int2* __restrict__ slotmap,
    const __half* __restrict__ pernode,
    const float* __restrict__ Wfold,
    const float* __restrict__ WN2, const float* __restrict__ bN2,
    const float* __restrict__ Wd, const float* __restrict__ bd,
    float* __restrict__ out_hmsg, float* __restrict__ out_ymsg,
    float* __restrict__ aggr_out) {
    __shared__ __half tile[256 * HSTRIDE];
    __shared__ int nid[256];
    int tid = threadIdx.x;
    int slot = blockIdx.x * 256 + tid;
    int2 sm = slotmap[slot];
    int e = sm.x;
    int src = eidx[e];

    float m[H], t[H], u[H];
    const __half2* pn = reinterpret_cast<const __half2*>(pernode + (size_t)src * 64);

    load_row32(h_msg + (size_t)e * H, m);
    load_row32_h(pn, t);
    matvec32_acc(m, Wfold, t);
#pragma unroll
    for (int o = 0; o < H; ++o) t[o] = lrelu(t[o]);

    matvec32(t, WN2, bN2, u);

    load_row32_h(pn + 16, t);
#pragma unroll
    for (int o = 0; o < H; ++o) m[o] = t[o] + lrelu(u[o]);

    store_row32(out_hmsg + (size_t)e * H, m);

    float z0 = bd[0], z1 = bd[1];
#pragma unroll
    for (int k = 0; k < H; ++k) {
        z0 = fmaf(m[k], Wd[k * 2 + 0], z0);
        z1 = fmaf(m[k], Wd[k * 2 + 1], z1);
    }
    float zm = fmaxf(z0, z1);
    float e0 = __expf(z0 - zm), e1 = __expf(z1 - zm);
    float inv = 1.0f / (e0 + e1);
    *reinterpret_cast<float2*>(out_ymsg + (size_t)e * 2) = make_float2(e0 * inv, e1 * inv);

    staged_segsum(m, sm.y, tid, tile, nid, aggr_out);
}

// ---------------- pernode + node_update (shared) ----------------
__global__ __launch_bounds__(256) void pernode_kernel(const float* __restrict__ x,
                                                      const float* __restrict__ raw,
                                                      const int* __restrict__ ptr,
                                                      const float* __restrict__ W_in,
                                                      const float* __restrict__ b_in,
                                                      const float* __restrict__ Wn1,
                                                      const float* __restrict__ bn1,
                                                      const float* __restrict__ Wn2,
                                                      const float* __restrict__ bn2,
                                                      const float* __restrict__ W2,
                                                      const float* __restrict__ c1,
                                                      const float* __restrict__ c0,
                                                      __half* __restrict__ pernode) {
    int i = blockIdx.x * blockDim.x + threadIdx.x;
    if (i >= N_NODES) return;
    float s[H], p1[H];
    __half2* row = reinterpret_cast<__half2*>(pernode + (size_t)i * 64);
    load_row32(raw + (size_t)i * H, s);
    float deg = (float)(ptr[i + 1] - ptr[i]);
#pragma unroll
    for (int o = 0; o < H; ++o) p1[o] = fmaf(deg, c1[o], c0[o]);
    matvec32_acc(s, W2, p1);
    store_row32_h(row, p1);
    hnode_row(x, i, W_in, b_in, s);
    matvec32(s, Wn1, bn1, p1);
#pragma unroll
    for (int o = 0; o < H; ++o) p1[o] = lrelu(p1[o]);
    matvec32(p1, Wn2, bn2, s);
#pragma unroll
    for (int o = 0; o < H; ++o) s[o] = lrelu(s[o]);
    store_row32_h(row + 16, s);
}

__global__ __launch_bounds__(256) void node_update_kernel(
    const float* __restrict__ x, const float* __restrict__ aggr_out,
    const float* __restrict__ W_in, const float* __restrict__ b_in,
    const float* __restrict__ WU, const float* __restrict__ bU,
    const float* __restrict__ Wb, const float* __restrict__ bb,
    float* __restrict__ out_beliefs) {
    int i = blockIdx.x * blockDim.x + threadIdx.x;
    if (i >= N_NODES) return;
    float a[H], t[H];
    hnode_row(x, i, W_in, b_in, a);
    matvec32(a, WU, bU, t);
    load_row32(aggr_out + (size_t)i * H, a);
    matvec32_acc(a, WU + H * H, t);
#pragma unroll
    for (int o = 0; o < H; ++o) t[o] = lrelu(t[o]);

    if (x[(size_t)i * 3] == 1.0f) {
        float z0 = bb[0], z1 = bb[1];
#pragma unroll
        for (int k = 0; k < H; ++k) {
            z0 = fmaf(t[k], Wb[k * 2 + 0], z0);
            z1 = fmaf(t[k], Wb[k * 2 + 1], z1);
        }
        float zm = fmaxf(z0, z1);
        float e0 = __expf(z0 - zm), e1 = __expf(z1 - zm);
        float inv = 1.0f / (e0 + e1);
        out_beliefs[(size_t)i * 2 + 0] = e0 * inv;
        out_beliefs[(size_t)i * 2 + 1] = e1 * inv;
    }
}

extern "C" void kernel_launch(void* const* d_in, const int* in_sizes, int n_in,
                              void* d_out, int out_size, void* d_ws, size_t ws_size,
                              hipStream_t stream) {
    const float* x     = (const float*)d_in[0];
    const int*   eidx  = (const int*)d_in[1];
    const float* h_msg = (const float*)d_in[2];
    const float* W_in = (const float*)d_in[3];  const float* b_in = (const float*)d_in[4];
    const float* We   = (const float*)d_in[5];  const float* be   = (const float*)d_in[6];
    const float* Wn1  = (const float*)d_in[7];  const float* bn1  = (const float*)d_in[8];
    const float* Wn2  = (const float*)d_in[9];  const float* bn2  = (const float*)d_in[10];
    const float* WN1  = (const float*)d_in[11]; const float* bN1  = (const float*)d_in[12];
    const float* WN2  = (const float*)d_in[13]; const float* bN2  = (const float*)d_in[14];
    const float* WU   = (const float*)d_in[15]; const float* bU   = (const float*)d_in[16];
    const float* Wd   = (const float*)d_in[17]; const float* bd   = (const float*)d_in[18];
    const float* Wb   = (const float*)d_in[19]; const float* bb   = (const float*)d_in[20];

    float* out         = (float*)d_out;
    float* out_hmsg    = out;
    float* out_ymsg    = out + (size_t)N_EDGES * H;
    float* out_beliefs = out + (size_t)N_EDGES * (H + 2);

    const int EB   = N_EDGES / 256;               // 12500 exact
    const int RAW4 = (N_NODES * H) / 4;

    // ---- big-path workspace layout ----
    const size_t SZ_PERNODE = (size_t)N_NODES * 64 * sizeof(__half);   // 12.8 MB
    const size_t SZ_RAW     = (size_t)N_NODES * H * sizeof(float);     // 12.8 MB
    const size_t SZ_SLOT4   = (size_t)N_EDGES * sizeof(int4);          // 51.2 MB
    const size_t SZ_HS      = (size_t)N_EDGES * H * sizeof(__half);    // 204.8 MB
    const size_t SZ_SMALL   = 4096 + 4096 + 128 + 128                  // W2,Wfold,c1,c0
                            + sizeof(int) * (N_NODES + (N_NODES + 1) + N_NODES + 512);
    const size_t NEED_BIG = SZ_PERNODE + SZ_RAW + SZ_SLOT4 + SZ_HS + SZ_SMALL + 1024;

    char* w = (char*)d_ws;
    __half* pernode = (__half*)w;                      w += SZ_PERNODE;
    float*  raw     = (float*)w;                       w += SZ_RAW;

    if (ws_size >= NEED_BIG) {
        // ======== PATH A ========
        int4*   slotmap4 = (int4*)w;                   w += SZ_SLOT4;
        __half* hs       = (__half*)w;                 w += SZ_HS;
        float*  W2       = (float*)w;                  w += 4096;
        float*  Wfold    = (float*)w;                  w += 4096;
        float*  c1       = (float*)w;                  w += 128;
        float*  c0       = (float*)w;                  w += 128;
        int*    cnt      = (int*)w;                    w += sizeof(int) * N_NODES;
        int*    ptr      = (int*)w;                    w += sizeof(int) * (N_NODES + 1);
        int*    fill     = (int*)w;                    w += sizeof(int) * N_NODES;
        int*    bsum     = (int*)w;

        fold_kernel<<<1, 1024, 0, stream>>>(We, be, WN1, bN1, W2, Wfold, c1, c0);

        zero_int_kernel<<<SCAN_BLOCKS, 256, 0, stream>>>(cnt, N_NODES);
        hist_kernel<<<EB, 256, 0, stream>>>(eidx, cnt);
        scan_block_kernel<<<SCAN_BLOCKS, 256, 0, stream>>>(cnt, ptr, bsum);
        scan_bsum_kernel<<<1, 512, 0, stream>>>(bsum, SCAN_BLOCKS);
        scan_fix_kernel<<<SCAN_BLOCKS, 256, 0, stream>>>(ptr, fill, bsum);
        scatter_big_kernel<<<EB, 256, 0, stream>>>(eidx, h_msg, fill, slotmap4, hs);

        zero_f4_kernel<<<(RAW4 + 255) / 256, 256, 0, stream>>>((float4*)raw, RAW4);
        seg_stage_big_kernel<<<EB, 256, 0, stream>>>(hs, slotmap4, raw);

        pernode_kernel<<<SCAN_BLOCKS, 256, 0, stream>>>(
            x, raw, ptr, W_in, b_in, Wn1, bn1, Wn2, bn2, W2, c1, c0, pernode);

        zero_f4_kernel<<<(RAW4 + 255) / 256, 256, 0, stream>>>((float4*)raw, RAW4);

        edge_fused_big_kernel<<<EB, 256, 0, stream>>>(
            hs, slotmap4, pernode, Wfold, WN2, bN2, Wd, bd,
            out_hmsg, out_ymsg, raw);

        node_update_kernel<<<SCAN_BLOCKS, 256, 0, stream>>>(
            x, raw, W_in, b_in, WU, bU, Wb, bb, out_beliefs);
    } else {
        // ======== PATH B (round-9 fallback) ========
        int2*   slotmap = (int2*)w;                    w += (size_t)N_EDGES * sizeof(int2);
        float*  W2      = (float*)w;                   w += 4096;
        float*  Wfold   = (float*)w;                   w += 4096;
        float*  c1      = (float*)w;                   w += 128;
        float*  c0      = (float*)w;                   w += 128;
        int*    cnt     = (int*)w;                     w += sizeof(int) * N_NODES;
        int*    ptr     = (int*)w;                     w += sizeof(int) * (N_NODES + 1);
        int*    fill    = (int*)w;                     w += sizeof(int) * N_NODES;
        int*    bsum    = (int*)w;

        fold_kernel<<<1, 1024, 0, stream>>>(We, be, WN1, bN1, W2, Wfold, c1, c0);

        zero_int_kernel<<<SCAN_BLOCKS, 256, 0, stream>>>(cnt, N_NODES);
        hist_kernel<<<EB, 256, 0, stream>>>(eidx, cnt);
        scan_block_kernel<<<SCAN_BLOCKS, 256, 0, stream>>>(cnt, ptr, bsum);
        scan_bsum_kernel<<<1, 512, 0, stream>>>(bsum, SCAN_BLOCKS);
        scan_fix_kernel<<<SCAN_BLOCKS, 256, 0, stream>>>(ptr, fill, bsum);
        scatter_kernel<<<EB, 256, 0, stream>>>(eidx, fill, slotmap);

        zero_f4_kernel<<<(RAW4 + 255) / 256, 256, 0, stream>>>((float4*)raw, RAW4);
        seg_stage_kernel<<<EB, 256, 0, stream>>>(h_msg, slotmap, raw);

        pernode_kernel<<<SCAN_BLOCKS, 256, 0, stream>>>(
            x, raw, ptr, W_in, b_in, Wn1, bn1, Wn2, bn2, W2, c1, c0, pernode);

        zero_f4_kernel<<<(RAW4 + 255) / 256, 256, 0, stream>>>((float4*)raw, RAW4);

        edge_fused_kernel<<<EB, 256, 0, stream>>>(
            h_msg, eidx, slotmap, pernode, Wfold, WN2, bN2, Wd, bd,
            out_hmsg, out_ymsg, raw);

        node_update_kernel<<<SCAN_BLOCKS, 256, 0, stream>>>(
            x, raw, W_in, b_in, WU, bU, Wb, bb, out_beliefs);
    }
}